// Round 7
// baseline (138.698 us; speedup 1.0000x reference)
//
#include <hip/hip_runtime.h>
#include <hip/hip_fp16.h>

// Problem constants (from reference setup_inputs)
#define N_TF    1024
#define N_GENES 20000
#define WW      4
#define FANIN   16
#define BATCH   128
#define HALF_B  64
#define EPG     (WW * FANIN)            // 64 edges per gene

// fused geometry: 512 persistent-ish blocks = 256 gene-blocks x 2 batch-halves,
// 1024 thr (16 waves), 1 resident block/CU (152 KiB LDS) -> exactly 2 blocks
// sequential per CU. Wave = 1 gene per task iteration.
#define NTHREADS 1024
#define NWAVES   16
#define NBLK     512
#define MAXG     80
#define YROW     65                     // floats; odd => (gl+bb)%32 banks, 2-way free
#define XH_BYTES (N_TF * HALF_B * 2)    // 131072
#define YT_BYTES (MAXG * YROW * 4)      // 20800
#define LDS_BYTES (XH_BYTES + YT_BYTES) // 151872 <= 160 KiB (worked in round 3)

typedef unsigned int uint32;

// ---------------------------------------------------------------------------
// Batched fast tanh for 2 values: 2x exp + ONE rcp (exact identity, fp32).
__device__ __forceinline__ float2 fast_tanh2(float a, float b) {
    const float ta = __expf(2.0f * a);
    const float tb = __expf(2.0f * b);
    const float da = ta + 1.0f;
    const float db = tb + 1.0f;
    const float r  = __builtin_amdgcn_rcpf(da * db);
    return make_float2(fmaf(-2.0f * db, r, 1.0f),
                       fmaf(-2.0f * da, r, 1.0f));
}

// ---------------------------------------------------------------------------
// features [B=128][N_TF=1024] fp32 -> xhs [half=2][N_TF=1024][64] fp16
// (batch pre-split into halves; 128 B rows, contiguous per half for LDS fill)
__global__ __launch_bounds__(256) void transpose_cvt_kernel(
    const float* __restrict__ in, __half* __restrict__ out)
{
    __shared__ float tile[32][33];
    const int bx = blockIdx.x;            // N_TF tile 0..31
    const int by = blockIdx.y;            // B tile 0..3
    const int tx = threadIdx.x;           // 0..31
    const int ty = threadIdx.y;           // 0..7
#pragma unroll
    for (int k = 0; k < 32; k += 8)
        tile[ty + k][tx] = in[(by * 32 + ty + k) * N_TF + bx * 32 + tx];
    __syncthreads();
    const int b  = by * 32 + tx;          // batch index
    const int h  = b >> 6;                // batch half
    const int bl = b & 63;                // index within half
#pragma unroll
    for (int k = 0; k < 32; k += 8) {
        const int tf = bx * 32 + ty + k;
        out[h * (N_TF * HALF_B) + tf * HALF_B + bl] = __float2half(tile[tx][ty + k]);
    }
}

// ---------------------------------------------------------------------------
// Fused 3-layer kernel, LDS-resident gather table (no L1-MSHR wall).
// Block: (gene-block gb of ~78 genes, batch-half h). xh half-slice in LDS.
// Wave = 1 gene/task: lane>>5 = edge parity (even/odd), lane&31 = batch pair.
// Each ds_read_b32 serves 2 edges (2 rows x 32 consecutive dwords) = 2 lanes
// per bank = conflict-free. Edge idx/weights are wave-uniform SGPRs.
__global__ __launch_bounds__(NTHREADS) void fused_kernel(
    const __half* __restrict__ xhs,    // [2][N_TF][64] fp16
    const int*    __restrict__ in1,    // [NNZ1]
    const float*  __restrict__ w1,     // [NNZ1]
    const float*  __restrict__ b1,     // [M]
    const float*  __restrict__ w2,     // [M*W]
    const float*  __restrict__ b2,     // [M]
    const float*  __restrict__ w3,     // [N_GENES*W]
    const float*  __restrict__ b3,     // [N_GENES]
    float*        __restrict__ out)    // [B][N_GENES]
{
    extern __shared__ char smem[];
    __half* xh = (__half*)smem;                  // [1024][64] fp16, 128 KiB
    float*  yt = (float*)(smem + XH_BYTES);      // [MAXG][YROW] fp32

    const int tid = threadIdx.x;
    const int bx  = blockIdx.x;
    const int h   = bx & 1;                      // batch half
    const int gb  = bx >> 1;                     // gene block 0..255
    const int g0  = gb * 78 + (gb < 32 ? gb : 32);
    const int ng  = 78 + (gb < 32 ? 1 : 0);

    // ---- fill xh slice from global (contiguous 128 KiB, streaming) ---------
    {
        const uint4* __restrict__ src = (const uint4*)(xhs + h * (N_TF * HALF_B));
        uint4* dst = (uint4*)xh;
#pragma unroll
        for (int i = 0; i < (XH_BYTES / 16) / NTHREADS; ++i)     // 8 iters
            dst[i * NTHREADS + tid] = src[i * NTHREADS + tid];
    }
    __syncthreads();

    const int wid  = __builtin_amdgcn_readfirstlane(tid >> 6);   // uniform
    const int lane = tid & 63;
    const int lsel = lane >> 5;        // 0: even edge of pair, 1: odd edge
    const int ll   = (lane & 31) << 2; // byte offset of this lane's __half2

    for (int gl = wid; gl < ng; gl += NWAVES) {
        const int g = g0 + gl;                                   // uniform
        const uint4*  __restrict__ ig = (const uint4*)(in1 + g * EPG);
        const float4* __restrict__ wg = (const float4*)(w1 + g * EPG);

        // ---- Layer 1: node i <- 16 edges = 8 pairs; parity-split lanes -----
        float2 h1[WW];
#pragma unroll
        for (int node = 0; node < WW; ++node) {
            __half2 xv[8], wv[8];
#pragma unroll
            for (int kk = 0; kk < 4; ++kk) {
                const uint4  iq = ig[node * 4 + kk];    // s_load: 4 edge idx
                const float4 wq = wg[node * 4 + kk];    // s_load: 4 weights
                // pair 2kk: edges (iq.x, iq.y)
                {
                    const int offA = (int)(iq.x << 7);  // idx*128 B (SALU)
                    const int offB = (int)(iq.y << 7);
                    const int off  = lsel ? offB : offA;          // v_cndmask
                    xv[2 * kk] = *(const __half2*)((const char*)xh + off + ll);
                    const float wf = lsel ? wq.y : wq.x;          // v_cndmask
                    wv[2 * kk] = __float2half2_rn(wf);
                }
                // pair 2kk+1: edges (iq.z, iq.w)
                {
                    const int offA = (int)(iq.z << 7);
                    const int offB = (int)(iq.w << 7);
                    const int off  = lsel ? offB : offA;
                    xv[2 * kk + 1] = *(const __half2*)((const char*)xh + off + ll);
                    const float wf = lsel ? wq.w : wq.z;
                    wv[2 * kk + 1] = __float2half2_rn(wf);
                }
            }
            __half2 acc = __float2half2_rn(0.0f);
#pragma unroll
            for (int t = 0; t < 8; ++t)
                acc = __hfma2(wv[t], xv[t], acc);
            // merge even/odd partial sums across half-waves (fp32)
            int ai;  __builtin_memcpy(&ai, &acc, 4);
            const int oi = __shfl_xor(ai, 32, 64);
            __half2 other;  __builtin_memcpy(&other, &oi, 4);
            const float2 af = __half22float2(acc);
            const float2 of = __half22float2(other);
            const float  bb = b1[g * WW + node];                  // s_load
            h1[node] = fast_tanh2(af.x + of.x + bb, af.y + of.y + bb);
        }

        // ---- Layer 2: dense 4x4 (weights via s_load) -----------------------
        float2 h2[WW];
#pragma unroll
        for (int i = 0; i < WW; ++i) {
            const float4 w  = *(const float4*)(w2 + g * 16 + i * 4);
            const float  bb = b2[g * WW + i];
            const float sx = bb + w.x * h1[0].x + w.y * h1[1].x
                                + w.z * h1[2].x + w.w * h1[3].x;
            const float sy = bb + w.x * h1[0].y + w.y * h1[1].y
                                + w.z * h1[2].y + w.w * h1[3].y;
            h2[i] = fast_tanh2(sx, sy);
        }

        // ---- Layer 3: sum 4 nodes ------------------------------------------
        const float4 wv3 = *(const float4*)(w3 + g * 4);
        const float  bv  = b3[g];
        const float yx = bv + wv3.x * h2[0].x + wv3.y * h2[1].x
                            + wv3.z * h2[2].x + wv3.w * h2[3].x;
        const float yy = bv + wv3.x * h2[0].y + wv3.y * h2[1].y
                            + wv3.z * h2[2].y + wv3.w * h2[3].y;

        // ---- stash to ytile (lanes 0-31; both halves hold identical y) -----
        if (lsel == 0) {
            const int q = lane & 31;
            float* yp = yt + gl * YROW + 2 * q;
            yp[0] = yx;                 // 2x ds_write_b32, banks (gl+2q)%32:
            yp[1] = yy;                 // 16 banks x 2 lanes = 2-way = free
        }
    }
    __syncthreads();

    // ---- coalesced store: rows of ng (~78) consecutive genes ---------------
#pragma unroll
    for (int r = 0; r < HALF_B / NWAVES; ++r) {                  // 4
        const int bb  = r * NWAVES + wid;                        // 0..63
        const int row = (h * HALF_B + bb) * N_GENES + g0;
        for (int gl = lane; gl < ng; gl += 64)
            out[row + gl] = yt[gl * YROW + bb];
    }
}

// ---------------------------------------------------------------------------
extern "C" void kernel_launch(void* const* d_in, const int* in_sizes, int n_in,
                              void* d_out, int out_size, void* d_ws, size_t ws_size,
                              hipStream_t stream)
{
    // order: features, w1, b1, w2, b2, w3, b3, out1, in1, out2, in2, out3, in3
    const float* features = (const float*)d_in[0];
    const float* w1 = (const float*)d_in[1];
    const float* b1 = (const float*)d_in[2];
    const float* w2 = (const float*)d_in[3];
    const float* b2 = (const float*)d_in[4];
    const float* w3 = (const float*)d_in[5];
    const float* b3 = (const float*)d_in[6];
    const int*   in1 = (const int*)d_in[8];
    float* out = (float*)d_out;

    __half* xhs = (__half*)d_ws;                 // [2][1024][64] fp16 = 256 KiB

    hipLaunchKernelGGL(transpose_cvt_kernel, dim3(32, 4), dim3(32, 8), 0, stream,
                       features, xhs);
    hipLaunchKernelGGL(fused_kernel, dim3(NBLK), dim3(NTHREADS), LDS_BYTES, stream,
                       xhs, in1, w1, b1, w2, b2, w3, b3, out);
}

// Round 9
// 118.438 us; speedup vs baseline: 1.1711x; 1.1711x over previous
//
#include <hip/hip_runtime.h>
#include <hip/hip_fp16.h>

// Problem constants (from reference setup_inputs)
#define N_TF    1024
#define N_GENES 20000
#define WW      4
#define FANIN   16
#define BATCH   128
#define EPG     (WW * FANIN)            // 64 edges per gene
#define MM      (N_GENES * WW)          // 80000 nodes
#define NNZ1    (N_GENES * EPG)

// fused geometry: 1 gene per wave, 16 waves (1024 thr) per block
#define GPB      16
#define NTHREADS 1024
#define NBLK     (N_GENES / GPB)        // 1250
#define YROW     (BATCH + 2)            // yt row stride (floats)

typedef unsigned int uint32;

// ---------------------------------------------------------------------------
// Batched fast tanh for 2 values: 2x exp + ONE rcp (exact identity, fp32).
__device__ __forceinline__ float2 fast_tanh2(float a, float b) {
    const float ta = __expf(2.0f * a);
    const float tb = __expf(2.0f * b);
    const float da = ta + 1.0f;
    const float db = tb + 1.0f;
    const float r  = __builtin_amdgcn_rcpf(da * db);
    return make_float2(fmaf(-2.0f * db, r, 1.0f),
                       fmaf(-2.0f * da, r, 1.0f));
}

__device__ __forceinline__ float cvt_ub0(uint32 v) {
#if __has_builtin(__builtin_amdgcn_cvt_f32_ubyte0)
    return __builtin_amdgcn_cvt_f32_ubyte0(v);
#else
    return (float)(v & 0xffu);
#endif
}
__device__ __forceinline__ float cvt_ub1(uint32 v) {
#if __has_builtin(__builtin_amdgcn_cvt_f32_ubyte1)
    return __builtin_amdgcn_cvt_f32_ubyte1(v);
#else
    return (float)((v >> 8) & 0xffu);
#endif
}

// ---------------------------------------------------------------------------
// prep1: one WAVE per TF row. Computes exact per-row [min,max] over the 128
// batch values, quantizes x = s*u + o (u in [0,255], o = min, s = range/255),
// writes xu [N_TF][128] u8 (128 B coalesced rows) + so[tf] = (s, o).
__global__ __launch_bounds__(512) void prep1_kernel(
    const float* __restrict__ features,      // [B][N_TF]
    unsigned char* __restrict__ xu,          // [N_TF][B]
    float2*       __restrict__ so)           // [N_TF] (scale, offset)
{
    const int wid  = threadIdx.x >> 6;       // 0..7
    const int lane = threadIdx.x & 63;
    const int tf   = blockIdx.x * 8 + wid;   // grid 128 -> 1024 rows

    const float a = features[(2 * lane)     * N_TF + tf];
    const float b = features[(2 * lane + 1) * N_TF + tf];
    float mn = fminf(a, b), mx = fmaxf(a, b);
#pragma unroll
    for (int off = 1; off < 64; off <<= 1) {
        mn = fminf(mn, __shfl_xor(mn, off, 64));
        mx = fmaxf(mx, __shfl_xor(mx, off, 64));
    }
    const float range = fmaxf(mx - mn, 1e-20f);
    const float inv   = 255.0f / range;
    const float s     = range * (1.0f / 255.0f);

    float va = fmaf(a - mn, inv, 0.5f);      // round-to-nearest via +0.5,trunc
    float vb = fmaf(b - mn, inv, 0.5f);
    va = fminf(fmaxf(va, 0.0f), 255.0f);
    vb = fminf(fmaxf(vb, 0.0f), 255.0f);
    const uint32 ua = (uint32)va;
    const uint32 ub = (uint32)vb;
    *(unsigned short*)(xu + tf * BATCH + 2 * lane) =
        (unsigned short)(ua | (ub << 8));

    if (lane == 0) so[tf] = make_float2(s, mn);
}

// ---------------------------------------------------------------------------
// prep2: one thread per node. Folds per-row quant algebra into weights/bias:
//   z = sum_j w_j x_rj = sum_j (w_j s_rj) u_rj + (b1 + sum_j w_j o_rj)
// so-table is 8 KB -> L1-resident gathers.
__global__ __launch_bounds__(256) void prep2_kernel(
    const int*    __restrict__ in1,
    const float*  __restrict__ w1,
    const float*  __restrict__ b1,
    const float2* __restrict__ so,
    float*        __restrict__ w1s,
    float*        __restrict__ b1p)
{
    const int n = blockIdx.x * 256 + threadIdx.x;
    if (n >= MM) return;
    float corr = 0.0f;
#pragma unroll
    for (int j = 0; j < FANIN; ++j) {
        const int    e   = n * FANIN + j;
        const int    idx = in1[e];
        const float  w   = w1[e];
        const float2 p   = so[idx];
        w1s[e] = w * p.x;
        corr  = fmaf(w, p.y, corr);
    }
    b1p[n] = b1[n] + corr;
}

// ---------------------------------------------------------------------------
// Fused 3-layer kernel (round-6 skeleton, u8 gather rows) — identical to
// round 8's; only the prep-side quantization changed (per-row scale folded
// into w1s/b1p, so this kernel is oblivious to it).
__global__ __launch_bounds__(NTHREADS, 4) void fused_kernel(
    const unsigned char* __restrict__ xu,   // [N_TF][128] u8
    const int*    __restrict__ in1,    // [NNZ1]
    const float*  __restrict__ w1s,    // [NNZ1]  (= w1 * s_row)
    const float*  __restrict__ b1p,    // [M]     (= b1 + sum w1*o_row)
    const float*  __restrict__ w2,     // [M*W]
    const float*  __restrict__ b2,     // [M]
    const float*  __restrict__ w3,     // [N_GENES*W]
    const float*  __restrict__ b3,     // [N_GENES]
    float*        __restrict__ out)    // [B][N_GENES]
{
    __shared__ float yt[GPB * YROW];   // 16*130*4 = 8320 B

    const int tid  = threadIdx.x;
    const int wid  = __builtin_amdgcn_readfirstlane(tid >> 6);   // uniform
    const int lane = tid & 63;
    const int g    = blockIdx.x * GPB + wid;                     // uniform
    const int voff = lane << 1;        // byte offset of this lane's u8-pair
    const char* xb = (const char*)xu;

    const uint4*  __restrict__ ig = (const uint4*)(in1 + g * EPG);  // 16 x uint4
    const float4* __restrict__ wg = (const float4*)(w1s + g * EPG); // 16 x float4

    float2 acc[WW];
#pragma unroll
    for (int i = 0; i < WW; ++i) acc[i] = make_float2(0.0f, 0.0f);

#pragma unroll
    for (int half = 0; half < 2; ++half) {
        // ---- uniform (SGPR) loads: 32 indices + 32 weights -----------------
        uint32 idx[32];
        float  wsc[32];
#pragma unroll
        for (int k = 0; k < 8; ++k) {
            const uint4  iq = ig[half * 8 + k];      // s_load_dwordx4
            const float4 wq = wg[half * 8 + k];      // s_load_dwordx4
            idx[k * 4 + 0] = iq.x;  idx[k * 4 + 1] = iq.y;
            idx[k * 4 + 2] = iq.z;  idx[k * 4 + 3] = iq.w;
            wsc[k * 4 + 0] = wq.x;  wsc[k * 4 + 1] = wq.y;
            wsc[k * 4 + 2] = wq.z;  wsc[k * 4 + 3] = wq.w;
        }
        // ---- issue 32 gathers (32-deep in flight), 2 sectors each ----------
        unsigned short xv[32];
#pragma unroll
        for (int t = 0; t < 32; ++t)
            xv[t] = *(const unsigned short*)(xb + (((size_t)idx[t]) << 7) + voff);
        // ---- consume: 2 cvt + 2 fma per edge, fp32 accumulation ------------
#pragma unroll
        for (int t = 0; t < 32; ++t) {
            const uint32 v  = (uint32)xv[t];
            const float  x0 = cvt_ub0(v);
            const float  x1 = cvt_ub1(v);
            const int tt = half * 32 + t;
            const int nd = tt >> 4;                   // node (layout node-major)
            acc[nd].x = fmaf(wsc[t], x0, acc[nd].x);  // v_fmac, SGPR src0
            acc[nd].y = fmaf(wsc[t], x1, acc[nd].y);
        }
    }

    float2 h1[WW];
#pragma unroll
    for (int i = 0; i < WW; ++i) {
        const float bb = b1p[g * WW + i];                            // s_load
        h1[i] = fast_tanh2(acc[i].x + bb, acc[i].y + bb);
    }

    // ---- Layer 2: dense 4x4 (weights via s_load) ---------------------------
    float2 h2[WW];
#pragma unroll
    for (int i = 0; i < WW; ++i) {
        const float4 w  = *(const float4*)(w2 + g * 16 + i * 4);     // s_load
        const float  bb = b2[g * WW + i];
        const float sx = bb + w.x * h1[0].x + w.y * h1[1].x
                            + w.z * h1[2].x + w.w * h1[3].x;
        const float sy = bb + w.x * h1[0].y + w.y * h1[1].y
                            + w.z * h1[2].y + w.w * h1[3].y;
        h2[i] = fast_tanh2(sx, sy);
    }

    // ---- Layer 3: sum 4 nodes ----------------------------------------------
    const float4 wv3 = *(const float4*)(w3 + g * 4);                 // s_load
    const float  bv  = b3[g];
    const float yx = bv + wv3.x * h2[0].x + wv3.y * h2[1].x
                        + wv3.z * h2[2].x + wv3.w * h2[3].x;
    const float yy = bv + wv3.x * h2[0].y + wv3.y * h2[1].y
                        + wv3.z * h2[2].y + wv3.w * h2[3].y;

    // ---- stash to LDS [gene][batch] ----------------------------------------
    float2* ytw = (float2*)(yt + wid * YROW);
    ytw[lane] = make_float2(yx, yy);

    __syncthreads();

    // ---- coalesced store: 16 consecutive genes per batch row (64 B runs) ---
    const int g0 = blockIdx.x * GPB;
#pragma unroll
    for (int it = 0; it < (BATCH * GPB) / NTHREADS; ++it) {          // 2
        const int idx = it * NTHREADS + tid;
        const int gq  = idx & (GPB - 1);
        const int b   = idx >> 4;
        out[b * N_GENES + g0 + gq] = yt[gq * YROW + b];
    }
}

// ---------------------------------------------------------------------------
extern "C" void kernel_launch(void* const* d_in, const int* in_sizes, int n_in,
                              void* d_out, int out_size, void* d_ws, size_t ws_size,
                              hipStream_t stream)
{
    // order: features, w1, b1, w2, b2, w3, b3, out1, in1, out2, in2, out3, in3
    const float* features = (const float*)d_in[0];
    const float* w1 = (const float*)d_in[1];
    const float* b1 = (const float*)d_in[2];
    const float* w2 = (const float*)d_in[3];
    const float* b2 = (const float*)d_in[4];
    const float* w3 = (const float*)d_in[5];
    const float* b3 = (const float*)d_in[6];
    const int*   in1 = (const int*)d_in[8];
    float* out = (float*)d_out;

    // ws layout: [xu 128 KiB][so 8 KiB][w1s 5 MiB][b1p 320 KB]
    unsigned char* xu  = (unsigned char*)d_ws;
    float2*        so  = (float2*)((char*)d_ws + (size_t)N_TF * BATCH);
    float*         w1s = (float*)((char*)so + (size_t)N_TF * sizeof(float2));
    float*         b1p = w1s + NNZ1;

    hipLaunchKernelGGL(prep1_kernel, dim3(N_TF / 8), dim3(512), 0, stream,
                       features, xu, so);
    hipLaunchKernelGGL(prep2_kernel, dim3((MM + 255) / 256), dim3(256), 0, stream,
                       in1, w1, b1, so, w1s, b1p);
    hipLaunchKernelGGL(fused_kernel, dim3(NBLK), dim3(NTHREADS), 0, stream,
                       xu, in1, w1s, b1p, w2, b2, w3, b3, out);
}